// Round 7
// baseline (260.509 us; speedup 1.0000x reference)
//
#include <hip/hip_runtime.h>
#include <hip/hip_bf16.h>
#include <cstdint>

typedef __attribute__((ext_vector_type(8))) short bf16x8;   // 8 bf16 in 4 VGPRs
typedef __attribute__((ext_vector_type(4))) float f32x4;
typedef unsigned short ushortT;
typedef unsigned int uintT;

#define LOG2E 1.4426950408889634f

static __device__ __forceinline__ ushortT f2bf(float x) {
  uintT u = __builtin_bit_cast(uintT, x);
  u += 0x7fffu + ((u >> 16) & 1u);          // RNE
  return (ushortT)(u >> 16);
}
static __device__ __forceinline__ uintT packbf(float lo, float hi) {
  return (uintT)f2bf(lo) | ((uintT)f2bf(hi) << 16);
}

static __device__ __forceinline__ float exp2_fast(float x) {
#if __has_builtin(__builtin_amdgcn_exp2f)
  return __builtin_amdgcn_exp2f(x);
#else
  float r;
  asm volatile("v_exp_f32 %0, %1" : "=v"(r) : "v"(x));
  return r;
#endif
}

// ---------------- Kernel A: vb[i] = bf16(value[i]), 8.4M elements ----------------
__global__ __launch_bounds__(256) void k_value_bf16(const float* __restrict__ value,
                                                    ushortT* __restrict__ vb) {
  size_t i = ((size_t)blockIdx.x * 256 + threadIdx.x) * 8;
  float4 a = *reinterpret_cast<const float4*>(value + i);
  float4 b = *reinterpret_cast<const float4*>(value + i + 4);
  uint4 o;
  o.x = packbf(a.x, a.y); o.y = packbf(a.z, a.w);
  o.z = packbf(b.x, b.y); o.w = packbf(b.z, b.w);
  *reinterpret_cast<uint4*>(vb + i) = o;
}

// ---------------- Kernel 0: WvT[d][k] = bf16(Wv[k][d]), 1024x1024 ----------------
__global__ __launch_bounds__(256) void k_transpose_wv(const float* __restrict__ Wv,
                                                      ushortT* __restrict__ WvT) {
  __shared__ float tile[64][65];
  int bd = blockIdx.x * 64;   // d tile
  int bk = blockIdx.y * 64;   // k tile
  int t = threadIdx.x;
  int col = t & 63;
  int r0 = t >> 6;            // 0..3
  for (int r = r0; r < 64; r += 4)
    tile[r][col] = Wv[(size_t)(bk + r) * 1024 + bd + col];
  __syncthreads();
  for (int r = r0; r < 64; r += 4)
    WvT[(size_t)(bd + r) * 1024 + bk + col] = f2bf(tile[col][r]);
}

// ---------------- Kernel 1: vt[b][d][j] = bf16( (value @ Wv + bv)[b,j,d] ) ----------------
// GEMM: M=8192 rows (b,j), N=1024 (d), K=1024. 128x128 tile, BK=32, 4 waves.
// A (vb) is pre-converted bf16: staging is pure uint4 copies.
__global__ __launch_bounds__(256) void k_vproj(const ushortT* __restrict__ vb,
                                               const ushortT* __restrict__ WvT,
                                               const float* __restrict__ bv,
                                               ushortT* __restrict__ vt) {
  __shared__ ushortT smem[128 * 136];        // 34.8 KB; staging + epilogue reuse
  ushortT* As = smem;                        // [128][40] bf16, pitch 40 (80B, 16B-aligned)
  ushortT* Bs = smem + 5120;                 // [128][40]
  int t = threadIdx.x;
  int l = t & 63, w = t >> 6;
  int gj0 = blockIdx.x * 128;                // global row (b*2048+j)
  int n0 = blockIdx.y * 128;                 // d
  int b = gj0 >> 11, j0 = gj0 & 2047;
  int wr = (w >> 1) * 64, wc = (w & 1) * 64;

  f32x4 acc[4][4];
#pragma unroll
  for (int i = 0; i < 4; ++i)
#pragma unroll
    for (int j = 0; j < 4; ++j) acc[i][j] = (f32x4)0.0f;

  for (int kt = 0; kt < 32; ++kt) {
    // stage A: vb rows gj0..+127, cols kt*32..+31 (bf16, uint4 copies)
    {
      int seg = t & 3;
#pragma unroll
      for (int pass = 0; pass < 2; ++pass) {
        int r = pass * 64 + (t >> 2);
        uint4 v = *reinterpret_cast<const uint4*>(vb + (size_t)(gj0 + r) * 1024 + kt * 32 + seg * 8);
        *reinterpret_cast<uint4*>(&As[r * 40 + seg * 8]) = v;
      }
    }
    // stage B: WvT rows n0..+127 (d), cols kt*32..+31
    {
      int seg = t & 3;
#pragma unroll
      for (int pass = 0; pass < 2; ++pass) {
        int r = pass * 64 + (t >> 2);
        uint4 v = *reinterpret_cast<const uint4*>(WvT + (size_t)(n0 + r) * 1024 + kt * 32 + seg * 8);
        *reinterpret_cast<uint4*>(&Bs[r * 40 + seg * 8]) = v;
      }
    }
    __syncthreads();
    bf16x8 af[4], bfr[4];
#pragma unroll
    for (int i = 0; i < 4; ++i)
      af[i] = *reinterpret_cast<const bf16x8*>(&As[(wr + 16 * i + (l & 15)) * 40 + (l >> 4) * 8]);
#pragma unroll
    for (int j = 0; j < 4; ++j)
      bfr[j] = *reinterpret_cast<const bf16x8*>(&Bs[(wc + 16 * j + (l & 15)) * 40 + (l >> 4) * 8]);
#pragma unroll
    for (int i = 0; i < 4; ++i)
#pragma unroll
      for (int j = 0; j < 4; ++j)
        acc[i][j] = __builtin_amdgcn_mfma_f32_16x16x32_bf16(af[i], bfr[j], acc[i][j], 0, 0, 0);
    __syncthreads();
  }

  // epilogue: transpose via LDS, Ct[d_local][j_local], pitch 136
#pragma unroll
  for (int jj = 0; jj < 4; ++jj) {
    int dl = wc + 16 * jj + (l & 15);
    float bvv = bv[n0 + dl];
#pragma unroll
    for (int ii = 0; ii < 4; ++ii) {
      int jl = wr + 16 * ii + (l >> 4) * 4;
      ushort4 u;
      u.x = f2bf(acc[ii][jj].x + bvv);
      u.y = f2bf(acc[ii][jj].y + bvv);
      u.z = f2bf(acc[ii][jj].z + bvv);
      u.w = f2bf(acc[ii][jj].w + bvv);
      *reinterpret_cast<ushort4*>(&smem[dl * 136 + jl]) = u;
    }
  }
  __syncthreads();
  {
    int dl = t >> 1, half = t & 1;
#pragma unroll
    for (int n = 0; n < 8; ++n) {
      uint4 v = *reinterpret_cast<const uint4*>(&smem[dl * 136 + half * 64 + n * 8]);
      *reinterpret_cast<uint4*>(vt + (size_t)(b * 1024 + n0 + dl) * 2048 + j0 + half * 64 + n * 8) = v;
    }
  }
}

// ---------------- Kernel 2: attention ----------------
// grid (Sq/64, B, H), 256 threads (4 waves). Per block: 64 q-rows of one (h,b).
// P generated directly in MFMA A-fragment registers (no P_lds).
// Wave w owns q-rows 16w..16w+15; lane computes p for row 16w+(l&15),
// j = kt*128 + kk*32 + (l>>4)*8 .. +7 — exactly its A-fragment slice.
__global__ __launch_bounds__(256) void k_attn(const float* __restrict__ query,
                                              const float* __restrict__ key,
                                              const float* __restrict__ Wq,
                                              const float* __restrict__ bq,
                                              const float* __restrict__ Wk,
                                              const ushortT* __restrict__ vt,
                                              float* __restrict__ out) {
  __shared__ float kx_s[2048];
  __shared__ float cl_s[64], ml_s[64];
  __shared__ float wred[16];
  __shared__ float rZ[64];
  __shared__ ushortT V_lds[2][64 * 136];

  int t = threadIdx.x;
  int l = t & 63, w = t >> 6;
  int q0 = blockIdx.x * 64;
  int b = blockIdx.y;
  int h = blockIdx.z;

  // head scalars (uniform; scalarized by compiler)
  float Ah = 0.f, Bkh = 0.f;
#pragma unroll 8
  for (int d = 0; d < 64; ++d) {
    float wk = Wk[h * 64 + d];
    Ah = fmaf(Wq[h * 64 + d], wk, Ah);
    Bkh = fmaf(bq[h * 64 + d], wk, Bkh);
  }

  // load kx into LDS, reduce min/max
  float kmx = -1e30f, kmn = 1e30f;
  for (int j = t; j < 2048; j += 256) {
    float v = key[b * 2048 + j];
    kx_s[j] = v;
    kmx = fmaxf(kmx, v); kmn = fminf(kmn, v);
  }
#pragma unroll
  for (int off = 32; off > 0; off >>= 1) {
    kmx = fmaxf(kmx, __shfl_xor(kmx, off));
    kmn = fminf(kmn, __shfl_xor(kmn, off));
  }
  if (l == 0) { wred[w] = kmx; wred[8 + w] = kmn; }
  __syncthreads();
  kmx = fmaxf(fmaxf(wred[0], wred[1]), fmaxf(wred[2], wred[3]));
  kmn = fminf(fminf(wred[8], wred[9]), fminf(wred[10], wred[11]));

  if (t < 64) {
    float qx = query[b * 2048 + q0 + t];
    float c = (Ah * qx + Bkh) * 0.125f;
    float m = fmaxf(c * kmx, c * kmn);
    cl_s[t] = c * LOG2E;
    ml_s[t] = m * LOG2E;
  }
  __syncthreads();

  int row = 16 * w + (l & 15);
  int kc8 = (l >> 4) * 8;                 // k-slice offset within a 32-chunk
  float cli = cl_s[row];
  float nmli = -ml_s[row];

  f32x4 acc[4];
#pragma unroll
  for (int d = 0; d < 4; ++d) acc[d] = (f32x4)0.0f;
  float zpart = 0.f;

  // V staging (double-buffered): thread t covers rows {p*16 + (t>>4)}, seg (t&15)
  int vseg = t & 15, vr4 = t >> 4;
  const ushortT* vbase = vt + (size_t)(b * 1024 + h * 64) * 2048;
  uint4 vreg[4];
#define VLOAD(KT)                                                                     \
  {                                                                                   \
    _Pragma("unroll")                                                                 \
    for (int p = 0; p < 4; ++p)                                                       \
      vreg[p] = *reinterpret_cast<const uint4*>(                                      \
          vbase + (size_t)(p * 16 + vr4) * 2048 + (KT) * 128 + vseg * 8);             \
  }
#define VSTORE(BUF)                                                                   \
  {                                                                                   \
    _Pragma("unroll")                                                                 \
    for (int p = 0; p < 4; ++p)                                                       \
      *reinterpret_cast<uint4*>(&V_lds[BUF][(p * 16 + vr4) * 136 + vseg * 8]) = vreg[p]; \
  }

  VLOAD(0); VSTORE(0);
  __syncthreads();

  for (int kt = 0; kt < 16; ++kt) {
    int cur = kt & 1;
    if (kt < 15) VLOAD(kt + 1);           // issue early; ds_write late (T14)
#pragma unroll
    for (int kk = 0; kk < 4; ++kk) {
      int jb = kt * 128 + kk * 32 + kc8;
      float4 x0 = *reinterpret_cast<const float4*>(&kx_s[jb]);
      float4 x1 = *reinterpret_cast<const float4*>(&kx_s[jb + 4]);
      float p0 = exp2_fast(fmaf(cli, x0.x, nmli));
      float p1 = exp2_fast(fmaf(cli, x0.y, nmli));
      float p2 = exp2_fast(fmaf(cli, x0.z, nmli));
      float p3 = exp2_fast(fmaf(cli, x0.w, nmli));
      float p4 = exp2_fast(fmaf(cli, x1.x, nmli));
      float p5 = exp2_fast(fmaf(cli, x1.y, nmli));
      float p6 = exp2_fast(fmaf(cli, x1.z, nmli));
      float p7 = exp2_fast(fmaf(cli, x1.w, nmli));
      zpart += ((p0 + p1) + (p2 + p3)) + ((p4 + p5) + (p6 + p7));
      union { bf16x8 v; uintT u[4]; } au;
      au.u[0] = packbf(p0, p1); au.u[1] = packbf(p2, p3);
      au.u[2] = packbf(p4, p5); au.u[3] = packbf(p6, p7);
#pragma unroll
      for (int db = 0; db < 4; ++db) {
        bf16x8 bb = *reinterpret_cast<const bf16x8*>(&V_lds[cur][(16 * db + (l & 15)) * 136 + kk * 32 + kc8]);
        acc[db] = __builtin_amdgcn_mfma_f32_16x16x32_bf16(au.v, bb, acc[db], 0, 0, 0);
      }
    }
    if (kt < 15) VSTORE(cur ^ 1);
    __syncthreads();
  }

  // per-wave Z reduction: lanes {l, l^16, l^32(,^48)} share row (l&15)
  zpart += __shfl_xor(zpart, 16);
  zpart += __shfl_xor(zpart, 32);
  if (l < 16) rZ[16 * w + l] = 1.0f / zpart;
  __syncthreads();

  // out layout: (H*B, Sq, D), n = h*4 + b
  size_t obase = ((size_t)(h * 4 + b) * 2048 + q0) * 64;
#pragma unroll
  for (int db = 0; db < 4; ++db) {
    int d = db * 16 + (l & 15);
#pragma unroll
    for (int r = 0; r < 4; ++r) {
      int i = 16 * w + (l >> 4) * 4 + r;
      out[obase + (size_t)i * 64 + d] = acc[db][r] * rZ[i];
    }
  }
}

extern "C" void kernel_launch(void* const* d_in, const int* in_sizes, int n_in,
                              void* d_out, int out_size, void* d_ws, size_t ws_size,
                              hipStream_t stream) {
  const float* query = (const float*)d_in[0];
  const float* key   = (const float*)d_in[1];
  const float* value = (const float*)d_in[2];
  const float* Wq    = (const float*)d_in[3];
  const float* bq    = (const float*)d_in[4];
  const float* Wk    = (const float*)d_in[5];
  // bk = d_in[6] cancels in softmax
  const float* Wv    = (const float*)d_in[7];
  const float* bv    = (const float*)d_in[8];
  float* out = (float*)d_out;

  ushortT* WvT = (ushortT*)d_ws;                      // 1024*1024 bf16 = 2 MB
  ushortT* vt  = (ushortT*)d_ws + 1024 * 1024;        // 4*1024*2048 bf16 = 16.8 MB
  // vb lives in d_out (33.5 MB f32): 16.8 MB bf16, consumed by k_vproj,
  // then d_out is fully rewritten by k_attn.
  ushortT* vb  = (ushortT*)d_out;

  k_value_bf16<<<dim3(4096), 256, 0, stream>>>(value, vb);
  k_transpose_wv<<<dim3(16, 16), 256, 0, stream>>>(Wv, WvT);
  k_vproj<<<dim3(64, 8), 256, 0, stream>>>(vb, WvT, bv, vt);
  k_attn<<<dim3(32, 4, 16), 256, 0, stream>>>(query, key, Wq, bq, Wk, vt, out);
}

// Round 9
// 241.879 us; speedup vs baseline: 1.0770x; 1.0770x over previous
//
#include <hip/hip_runtime.h>
#include <cstdint>

// Moment-expansion cross-attention (rank-1 logits):
//   x_ij = c_i * kx_j,  c_i = (Ah*qx_i + Bkh)/8
//   out  = [sum_t (c'^t/t!) PW_t] / [sum_t (c'^t/t!) zeta_t] + bv
// with k-hat = kx/S_b, c' = c*S_b, T=72 Taylor terms, all f32.
// ws layout (floats): [0..3] S_b | [4..19] Ah | [20..35] Bkh | [64..351] zco[b][72]
//   | [1024 +) P[b][t][c] 294912 | [295936 +) PW[b][t][hd] 294912
//   | [590848 +) cz[(h*4+b)*2048+i]{c',rZ} 262144       (total 3.4 MB)
// d_out staging: k_mom partials [b][jc][t][c] 18.9MB -> consumed by k_red;
//   k_proj partials [cc][b][t][hd] 18.9MB -> consumed by k_projred;
//   k_out finally overwrites d_out completely.

#define WS_P   1024
#define WS_PW  295936
#define WS_CZ  590848

// ---- k_prep: per-b S_b=max|kx|, zco[b][t]=sum_j khat^t; Ah/Bkh per head ----
__global__ __launch_bounds__(256) void k_prep(const float* __restrict__ key,
                                              const float* __restrict__ Wq,
                                              const float* __restrict__ bq,
                                              const float* __restrict__ Wk,
                                              float* __restrict__ ws) {
  __shared__ float kxl[2048];
  __shared__ float wmax[4];
  __shared__ float wz[4][72];
  int t = threadIdx.x, l = t & 63, w = t >> 6;
  int b = blockIdx.x;
  float m = 0.f;
  for (int j = t; j < 2048; j += 256) {
    float v = key[b * 2048 + j];
    kxl[j] = v;
    m = fmaxf(m, fabsf(v));
  }
  for (int off = 32; off; off >>= 1) m = fmaxf(m, __shfl_xor(m, off));
  if (l == 0) wmax[w] = m;
  __syncthreads();
  float S = fmaxf(fmaxf(wmax[0], wmax[1]), fmaxf(wmax[2], wmax[3]));
  if (t == 0) ws[b] = S;
  float rs = 1.0f / S;

  float z[72];
#pragma unroll
  for (int q = 0; q < 72; ++q) z[q] = 0.f;
  for (int jj = 0; jj < 8; ++jj) {
    float kh = kxl[t * 8 + jj] * rs;
    float p = 1.f;
#pragma unroll
    for (int q = 0; q < 72; ++q) { z[q] += p; p *= kh; }
  }
#pragma unroll
  for (int q = 0; q < 72; ++q) {
    float v = z[q];
    for (int off = 32; off; off >>= 1) v += __shfl_xor(v, off);
    if (l == 0) wz[w][q] = v;
  }
  __syncthreads();
  if (t < 72) ws[64 + b * 72 + t] = wz[0][t] + wz[1][t] + wz[2][t] + wz[3][t];

  if (b == 0 && t < 32) {           // Ah (t<16) / Bkh (t>=16)
    int h = t & 15; bool isB = t >= 16;
    float a = 0.f;
    for (int d = 0; d < 64; ++d)
      a = fmaf(isB ? bq[h * 64 + d] : Wq[h * 64 + d], Wk[h * 64 + d], a);
    ws[4 + (isB ? 16 : 0) + h] = a;
  }
}

// ---- k_mom: part[b][jc][t][c] = sum_{j in chunk} khat^t * value[b,j,c] ----
__global__ __launch_bounds__(256) void k_mom(const float* __restrict__ value,
                                             const float* __restrict__ key,
                                             const float* __restrict__ ws,
                                             float* __restrict__ part) {
  __shared__ float khl[128];
  int tid = threadIdx.x;
  int ct = blockIdx.x, jc = blockIdx.y, b = blockIdx.z;
  int c = ct * 256 + tid;
  float rs = 1.0f / ws[b];
  if (tid < 128) khl[tid] = key[b * 2048 + jc * 128 + tid] * rs;
  __syncthreads();

  float acc[72];
#pragma unroll
  for (int q = 0; q < 72; ++q) acc[q] = 0.f;
  const float* vp = value + ((size_t)(b * 2048 + jc * 128) << 10) + c;
  for (int j4 = 0; j4 < 128; j4 += 4) {
    float v0 = vp[(size_t)(j4 + 0) << 10];
    float v1 = vp[(size_t)(j4 + 1) << 10];
    float v2 = vp[(size_t)(j4 + 2) << 10];
    float v3 = vp[(size_t)(j4 + 3) << 10];
#pragma unroll
    for (int u = 0; u < 4; ++u) {
      float v = (u == 0) ? v0 : (u == 1) ? v1 : (u == 2) ? v2 : v3;
      float kh = khl[j4 + u];
      float k2 = kh * kh;
      float q0 = 1.f, q1 = kh, q2 = k2, q3 = k2 * kh;
      float k4 = k2 * k2;
#pragma unroll
      for (int g = 0; g < 18; ++g) {   // 4 independent power chains (latency)
        acc[4 * g + 0] = fmaf(q0, v, acc[4 * g + 0]);
        acc[4 * g + 1] = fmaf(q1, v, acc[4 * g + 1]);
        acc[4 * g + 2] = fmaf(q2, v, acc[4 * g + 2]);
        acc[4 * g + 3] = fmaf(q3, v, acc[4 * g + 3]);
        q0 *= k4; q1 *= k4; q2 *= k4; q3 *= k4;
      }
    }
  }
  size_t base = ((size_t)((b * 16 + jc) * 72) << 10) + c;
#pragma unroll
  for (int q = 0; q < 72; ++q) part[base + ((size_t)q << 10)] = acc[q];
}

// ---- k_red: P[b][t][c] = sum_jc part ----
__global__ __launch_bounds__(256) void k_red(const float* __restrict__ part,
                                             float* __restrict__ ws) {
  int gid = blockIdx.x * 256 + threadIdx.x;     // < 294912
  int c = gid & 1023; int bt = gid >> 10; int t = bt % 72; int b = bt / 72;
  float s = 0.f;
  for (int jc = 0; jc < 16; ++jc)
    s += part[((size_t)((b * 16 + jc) * 72 + t) << 10) + c];
  ws[WS_P + ((size_t)(b * 72 + t) << 10) + c] = s;
}

// ---- k_proj: pp[cc][b][t][hd] = sum_{c in chunk} P[b][t][c] * Wv[c][hd] ----
// P chunk (72x64 = 18KB) staged in LDS once per block; reads are broadcast.
__global__ __launch_bounds__(256) void k_proj(const float* __restrict__ ws,
                                              const float* __restrict__ Wv,
                                              float* __restrict__ pp) {
  __shared__ float Pl[72 * 64];
  int tid = threadIdx.x;
  int cc = blockIdx.x, hdt = blockIdx.y, b = blockIdx.z;
  int hd = hdt * 256 + tid;
  for (int x = tid; x < 72 * 64; x += 256) {
    int q = x >> 6, c = x & 63;
    Pl[x] = ws[WS_P + ((size_t)(b * 72 + q) << 10) + cc * 64 + c];
  }
  __syncthreads();
  float acc[72];
#pragma unroll
  for (int q = 0; q < 72; ++q) acc[q] = 0.f;
  for (int c = 0; c < 64; ++c) {
    float wv = Wv[((size_t)(cc * 64 + c) << 10) + hd];
#pragma unroll
    for (int q = 0; q < 72; ++q)
      acc[q] = fmaf(Pl[(q << 6) + c], wv, acc[q]);
  }
  size_t base = ((size_t)((cc * 4 + b) * 72) << 10) + hd;
#pragma unroll
  for (int q = 0; q < 72; ++q) pp[base + ((size_t)q << 10)] = acc[q];
}

// ---- k_projred: PW[b][t][hd] = sum_cc pp ----
__global__ __launch_bounds__(256) void k_projred(const float* __restrict__ pp,
                                                 float* __restrict__ ws) {
  int gid = blockIdx.x * 256 + threadIdx.x;
  int hd = gid & 1023; int bt = gid >> 10; int t = bt % 72; int b = bt / 72;
  float s = 0.f;
  for (int cc = 0; cc < 16; ++cc)
    s += pp[((size_t)((cc * 4 + b) * 72 + t) << 10) + hd];
  ws[WS_PW + ((size_t)(b * 72 + t) << 10) + hd] = s;
}

// ---- k_z: per (h,b,i): c' and 1/Z via nested Horner over zco ----
__global__ __launch_bounds__(256) void k_z(const float* __restrict__ query,
                                           float* __restrict__ ws) {
  int bid = blockIdx.x;                 // 512
  int h = bid >> 5; int b = (bid >> 3) & 3; int it = bid & 7;
  int i = it * 256 + threadIdx.x;
  float S = ws[b];
  float Ah = ws[4 + h], Bkh = ws[20 + h];
  float qx = query[b * 2048 + i];
  float cp = fmaf(Ah, qx, Bkh) * 0.125f * S;
  const float* zc = ws + 64 + b * 72;
  float r = zc[71];
#pragma unroll
  for (int t = 71; t >= 1; --t)
    r = fmaf(cp * (1.0f / (float)t), r, zc[t - 1]);   // r = z_{t-1} + (c'/t) r
  float rz = 1.0f / r;
  size_t o = ((size_t)((h * 4 + b) * 2048 + i)) * 2;
  ws[WS_CZ + o] = cp;
  ws[WS_CZ + o + 1] = rz;
}

// ---- k_out: out[(h*4+b), i, d] = Horner(PW)/Z + bv ----
__global__ __launch_bounds__(256) void k_out(const float* __restrict__ ws,
                                             const float* __restrict__ bv,
                                             float* __restrict__ out) {
  int tid = threadIdx.x; int l = tid & 63; int w = tid >> 6;
  int qt = blockIdx.x, b = blockIdx.y, h = blockIdx.z;
  float a[72];
  const float* PW = ws + WS_PW + ((size_t)(b * 72) << 10) + h * 64 + l;
#pragma unroll
  for (int q = 0; q < 72; ++q) a[q] = PW[(size_t)q << 10];
  float bvd = bv[h * 64 + l];
  const float* cz = ws + WS_CZ + ((size_t)((h * 4 + b) * 2048 + qt * 256 + w * 64)) * 2;
  size_t ob = (((size_t)((h * 4 + b) * 2048) + qt * 256 + w * 64) << 6) + l;
  for (int r = 0; r < 64; ++r) {
    float cp = cz[r * 2], rz = cz[r * 2 + 1];
    float acc = a[71];
#pragma unroll
    for (int t = 71; t >= 1; --t)
      acc = fmaf(cp * (1.0f / (float)t), acc, a[t - 1]);
    out[ob + ((size_t)r << 6)] = fmaf(acc, rz, bvd);
  }
}

extern "C" void kernel_launch(void* const* d_in, const int* in_sizes, int n_in,
                              void* d_out, int out_size, void* d_ws, size_t ws_size,
                              hipStream_t stream) {
  const float* query = (const float*)d_in[0];
  const float* key   = (const float*)d_in[1];
  const float* value = (const float*)d_in[2];
  const float* Wq    = (const float*)d_in[3];
  const float* bq    = (const float*)d_in[4];
  const float* Wk    = (const float*)d_in[5];
  // bk = d_in[6] cancels in softmax
  const float* Wv    = (const float*)d_in[7];
  const float* bv    = (const float*)d_in[8];
  float* out = (float*)d_out;
  float* ws  = (float*)d_ws;
  float* stage = (float*)d_out;   // 18.9MB partial staging, overwritten by k_out

  k_prep<<<dim3(4), 256, 0, stream>>>(key, Wq, bq, Wk, ws);
  k_mom<<<dim3(4, 16, 4), 256, 0, stream>>>(value, key, ws, stage);
  k_red<<<dim3(1152), 256, 0, stream>>>(stage, ws);
  k_proj<<<dim3(16, 4, 4), 256, 0, stream>>>(ws, Wv, stage);
  k_projred<<<dim3(1152), 256, 0, stream>>>(stage, ws);
  k_z<<<dim3(512), 256, 0, stream>>>(query, ws);
  k_out<<<dim3(8, 4, 16), 256, 0, stream>>>(ws, bv, out);
}

// Round 10
// 183.900 us; speedup vs baseline: 1.4166x; 1.3153x over previous
//
#include <hip/hip_runtime.h>
#include <cstdint>

// Moment-expansion cross-attention (rank-1 logits), T=48 Taylor terms, all f32.
//   x_ij = c_i * kx_j,  c_i = (Ah*qx_i + Bkh)/8,  c' = c*S_b, khat = kx/S_b
//   out  = [sum_t (c'^t/t!) PW_t] / [sum_t (c'^t/t!) zeta_t] + bv
// ws (floats): [0..3] S_b | [4..19] Ah | [20..35] Bkh | [64..255] zco[b][48]
//   | WS_P  = 1024:   P[b][t][c]   4*48*1024 = 196608
//   | WS_PW = 197632: PW[b][t][hd] 196608
//   | WS_CZ = 394240: cz[(h*4+b)*2048+i]{c',rZ} 262144   (end 656384 fl = 2.6 MB)
// d_out staging: k_mom partials [b][jc32][t][c] 25.2MB -> consumed by k_red;
//   k_proj partials [cc][b][t][hd] 12.6MB -> consumed by k_projred;
//   k_out overwrites d_out completely afterwards.

#define WS_P   1024
#define WS_PW  197632
#define WS_CZ  394240

// ---- k_prep: per-b S_b=max|kx|, zco[b][t]=sum_j khat^t; Ah/Bkh per head ----
__global__ __launch_bounds__(256) void k_prep(const float* __restrict__ key,
                                              const float* __restrict__ Wq,
                                              const float* __restrict__ bq,
                                              const float* __restrict__ Wk,
                                              float* __restrict__ ws) {
  __shared__ float kxl[2048];
  __shared__ float wmax[4];
  __shared__ float wz[4][48];
  int t = threadIdx.x, l = t & 63, w = t >> 6;
  int b = blockIdx.x;
  float m = 0.f;
  for (int j = t; j < 2048; j += 256) {
    float v = key[b * 2048 + j];
    kxl[j] = v;
    m = fmaxf(m, fabsf(v));
  }
  for (int off = 32; off; off >>= 1) m = fmaxf(m, __shfl_xor(m, off));
  if (l == 0) wmax[w] = m;
  __syncthreads();
  float S = fmaxf(fmaxf(wmax[0], wmax[1]), fmaxf(wmax[2], wmax[3]));
  if (t == 0) ws[b] = S;
  float rs = 1.0f / S;

  float z[48];
#pragma unroll
  for (int q = 0; q < 48; ++q) z[q] = 0.f;
  for (int jj = 0; jj < 8; ++jj) {
    float kh = kxl[t * 8 + jj] * rs;
    float p = 1.f;
#pragma unroll
    for (int q = 0; q < 48; ++q) { z[q] += p; p *= kh; }
  }
#pragma unroll
  for (int q = 0; q < 48; ++q) {
    float v = z[q];
    for (int off = 32; off; off >>= 1) v += __shfl_xor(v, off);
    if (l == 0) wz[w][q] = v;
  }
  __syncthreads();
  if (t < 48) ws[64 + b * 48 + t] = wz[0][t] + wz[1][t] + wz[2][t] + wz[3][t];

  if (b == 0 && t < 32) {           // Ah (t<16) / Bkh (t>=16)
    int h = t & 15; bool isB = t >= 16;
    float a = 0.f;
    for (int d = 0; d < 64; ++d)
      a = fmaf(isB ? bq[h * 64 + d] : Wq[h * 64 + d], Wk[h * 64 + d], a);
    ws[4 + (isB ? 16 : 0) + h] = a;
  }
}

// ---- k_mom: part[b][jc][t][c] = sum_{j in 64-chunk} khat^t * value[b,j,c] ----
// grid (4 ct, 32 jc, 4 b) = 512 blocks (2/CU). acc[48] ~70 VGPR, no spill.
__global__ __launch_bounds__(256) void k_mom(const float* __restrict__ value,
                                             const float* __restrict__ key,
                                             const float* __restrict__ ws,
                                             float* __restrict__ part) {
  __shared__ float khl[64];
  int tid = threadIdx.x;
  int ct = blockIdx.x, jc = blockIdx.y, b = blockIdx.z;
  int c = ct * 256 + tid;
  float rs = 1.0f / ws[b];
  if (tid < 64) khl[tid] = key[b * 2048 + jc * 64 + tid] * rs;
  __syncthreads();

  float acc[48];
#pragma unroll
  for (int q = 0; q < 48; ++q) acc[q] = 0.f;
  const float* vp = value + ((size_t)(b * 2048 + jc * 64) << 10) + c;
  for (int j4 = 0; j4 < 64; j4 += 4) {
    float v0 = vp[(size_t)(j4 + 0) << 10];
    float v1 = vp[(size_t)(j4 + 1) << 10];
    float v2 = vp[(size_t)(j4 + 2) << 10];
    float v3 = vp[(size_t)(j4 + 3) << 10];
#pragma unroll
    for (int u = 0; u < 4; ++u) {
      float v = (u == 0) ? v0 : (u == 1) ? v1 : (u == 2) ? v2 : v3;
      float kh = khl[j4 + u];
      float k2 = kh * kh;
      float q0 = 1.f, q1 = kh, q2 = k2, q3 = k2 * kh;
      float k4 = k2 * k2;
#pragma unroll
      for (int g = 0; g < 12; ++g) {   // 4 independent power chains
        acc[4 * g + 0] = fmaf(q0, v, acc[4 * g + 0]);
        acc[4 * g + 1] = fmaf(q1, v, acc[4 * g + 1]);
        acc[4 * g + 2] = fmaf(q2, v, acc[4 * g + 2]);
        acc[4 * g + 3] = fmaf(q3, v, acc[4 * g + 3]);
        q0 *= k4; q1 *= k4; q2 *= k4; q3 *= k4;
      }
    }
  }
  size_t base = ((size_t)((b * 32 + jc) * 48) << 10) + c;
#pragma unroll
  for (int q = 0; q < 48; ++q) part[base + ((size_t)q << 10)] = acc[q];
}

// ---- k_red: P[b][t][c] = sum_jc part ----
__global__ __launch_bounds__(256) void k_red(const float* __restrict__ part,
                                             float* __restrict__ ws) {
  int gid = blockIdx.x * 256 + threadIdx.x;     // < 196608
  int c = gid & 1023; int bt = gid >> 10; int t = bt % 48; int b = bt / 48;
  float s = 0.f;
  for (int jc = 0; jc < 32; ++jc)
    s += part[((size_t)((b * 32 + jc) * 48 + t) << 10) + c];
  ws[WS_P + ((size_t)(b * 48 + t) << 10) + c] = s;
}

// ---- k_proj: pp[cc][b][t][hd] = sum_{c in chunk} P[b][t][c]*Wv[c][hd] ----
// grid (16 cc, 4 hdt, 12 = 4b*3tt). 16 t's per block: acc[16], no spill.
__global__ __launch_bounds__(256) void k_proj(const float* __restrict__ ws,
                                              const float* __restrict__ Wv,
                                              float* __restrict__ pp) {
  __shared__ float Pl[16 * 64];
  int tid = threadIdx.x;
  int cc = blockIdx.x, hdt = blockIdx.y;
  int b = blockIdx.z & 3, tt = blockIdx.z >> 2;
  int hd = hdt * 256 + tid;
  for (int x = tid; x < 16 * 64; x += 256) {
    int q = x >> 6, cl = x & 63;
    Pl[x] = ws[WS_P + ((size_t)(b * 48 + tt * 16 + q) << 10) + cc * 64 + cl];
  }
  __syncthreads();
  float acc[16];
#pragma unroll
  for (int q = 0; q < 16; ++q) acc[q] = 0.f;
  for (int c = 0; c < 64; ++c) {
    float wv = Wv[((size_t)(cc * 64 + c) << 10) + hd];
#pragma unroll
    for (int q = 0; q < 16; ++q)
      acc[q] = fmaf(Pl[(q << 6) + c], wv, acc[q]);   // broadcast LDS reads
  }
  size_t base = ((size_t)((cc * 4 + b) * 48 + tt * 16) << 10) + hd;
#pragma unroll
  for (int q = 0; q < 16; ++q) pp[base + ((size_t)q << 10)] = acc[q];
}

// ---- k_projred: PW[b][t][hd] = sum_cc pp ----
__global__ __launch_bounds__(256) void k_projred(const float* __restrict__ pp,
                                                 float* __restrict__ ws) {
  int gid = blockIdx.x * 256 + threadIdx.x;     // < 196608
  int hd = gid & 1023; int bt = gid >> 10; int t = bt % 48; int b = bt / 48;
  float s = 0.f;
  for (int cc = 0; cc < 16; ++cc)
    s += pp[((size_t)((cc * 4 + b) * 48 + t) << 10) + hd];
  ws[WS_PW + ((size_t)(b * 48 + t) << 10) + hd] = s;
}

// ---- k_z: per (h,b,i): c' and 1/Z via nested Horner over zco ----
__global__ __launch_bounds__(256) void k_z(const float* __restrict__ query,
                                           float* __restrict__ ws) {
  int bid = blockIdx.x;                 // 512
  int h = bid >> 5; int b = (bid >> 3) & 3; int it = bid & 7;
  int i = it * 256 + threadIdx.x;
  float S = ws[b];
  float Ah = ws[4 + h], Bkh = ws[20 + h];
  float qx = query[b * 2048 + i];
  float cp = fmaf(Ah, qx, Bkh) * 0.125f * S;
  const float* zc = ws + 64 + b * 48;
  float r = zc[47];
#pragma unroll
  for (int t = 47; t >= 1; --t)
    r = fmaf(cp * (1.0f / (float)t), r, zc[t - 1]);   // r = z_{t-1} + (c'/t) r
  float rz = 1.0f / r;
  size_t o = ((size_t)((h * 4 + b) * 2048 + i)) * 2;
  ws[WS_CZ + o] = cp;
  ws[WS_CZ + o + 1] = rz;
}

// ---- k_out: out[(h*4+b), i, d] = Horner(PW)/Z + bv ----
__global__ __launch_bounds__(256) void k_out(const float* __restrict__ ws,
                                             const float* __restrict__ bv,
                                             float* __restrict__ out) {
  int tid = threadIdx.x; int l = tid & 63; int w = tid >> 6;
  int qt = blockIdx.x, b = blockIdx.y, h = blockIdx.z;
  float a[48];
  const float* PW = ws + WS_PW + ((size_t)(b * 48) << 10) + h * 64 + l;
#pragma unroll
  for (int q = 0; q < 48; ++q) a[q] = PW[(size_t)q << 10];
  float bvd = bv[h * 64 + l];
  const float* cz = ws + WS_CZ + ((size_t)((h * 4 + b) * 2048 + qt * 256 + w * 64)) * 2;
  size_t ob = (((size_t)((h * 4 + b) * 2048) + qt * 256 + w * 64) << 6) + l;
  for (int r = 0; r < 64; ++r) {
    float cp = cz[r * 2], rz = cz[r * 2 + 1];
    float acc = a[47];
#pragma unroll
    for (int t = 47; t >= 1; --t)
      acc = fmaf(cp * (1.0f / (float)t), acc, a[t - 1]);
    out[ob + ((size_t)r << 6)] = fmaf(acc, rz, bvd);
  }
}

extern "C" void kernel_launch(void* const* d_in, const int* in_sizes, int n_in,
                              void* d_out, int out_size, void* d_ws, size_t ws_size,
                              hipStream_t stream) {
  const float* query = (const float*)d_in[0];
  const float* key   = (const float*)d_in[1];
  const float* value = (const float*)d_in[2];
  const float* Wq    = (const float*)d_in[3];
  const float* bq    = (const float*)d_in[4];
  const float* Wk    = (const float*)d_in[5];
  // bk = d_in[6] cancels in softmax
  const float* Wv    = (const float*)d_in[7];
  const float* bv    = (const float*)d_in[8];
  float* out = (float*)d_out;
  float* ws  = (float*)d_ws;
  float* stage = (float*)d_out;   // partial staging, overwritten by k_out

  k_prep<<<dim3(4), 256, 0, stream>>>(key, Wq, bq, Wk, ws);
  k_mom<<<dim3(4, 32, 4), 256, 0, stream>>>(value, key, ws, stage);
  k_red<<<dim3(768), 256, 0, stream>>>(stage, ws);
  k_proj<<<dim3(16, 4, 12), 256, 0, stream>>>(ws, Wv, stage);
  k_projred<<<dim3(768), 256, 0, stream>>>(stage, ws);
  k_z<<<dim3(512), 256, 0, stream>>>(query, ws);
  k_out<<<dim3(8, 4, 16), 256, 0, stream>>>(ws, bv, out);
}